// Round 1
// baseline (51.722 us; speedup 1.0000x reference)
//
#include <hip/hip_runtime.h>

// WHXE loss: one-pass column-partial reduction.
//   colS[n] = sum_b lam[n] * logp[b,n] * true[b,n]
//   cnt[n]  = sum_b true[b,n]
//   loss    = -(1/B) * sum_n (B / (N*(cnt[n]+eps))) * colS[n]
// Sibling groups are 4 consecutive columns (group_ids = repeat(arange(32),4)),
// so one float4 load = one complete softmax group.

#define B_TOTAL 131072
#define N_NODES 128
#define ALPHA   0.5f
#define EPS     1e-10f

constexpr int BLOCKS  = 1024;   // 4 waves/block * 1024 = 16 waves/CU, enough to saturate HBM
constexpr int THREADS = 256;
constexpr int ROWS_PER_ITER = THREADS / 32;   // 8 rows per block-iteration

__global__ __launch_bounds__(THREADS) void whxe_pass1(
    const float* __restrict__ logits,
    const float* __restrict__ truev,
    const float* __restrict__ depths,
    float* __restrict__ ws)          // ws[0..127]=colS, ws[128..255]=cnt
{
    const int t    = threadIdx.x;
    const int cg   = t & 31;         // column group 0..31 (4 cols each)
    const int rsub = t >> 5;         // row-within-iteration 0..7
    const int c0   = cg << 2;        // first column of this thread's group

    // per-column lambda = exp(-alpha * depth); fixed per thread
    float lam[4];
#pragma unroll
    for (int i = 0; i < 4; ++i) lam[i] = __expf(-ALPHA * depths[c0 + i]);

    float colS[4] = {0.f, 0.f, 0.f, 0.f};
    float cnt [4] = {0.f, 0.f, 0.f, 0.f};

    for (int r = blockIdx.x * ROWS_PER_ITER + rsub; r < B_TOTAL;
         r += gridDim.x * ROWS_PER_ITER) {
        const size_t base = (size_t)r * N_NODES + c0;
        const float4 x  = *reinterpret_cast<const float4*>(logits + base);
        const float4 tv = *reinterpret_cast<const float4*>(truev  + base);

        const float e0 = __expf(x.x), e1 = __expf(x.y),
                    e2 = __expf(x.z), e3 = __expf(x.w);
        const float ld = __logf(e0 + e1 + e2 + e3 + EPS);  // log(group denom)

        colS[0] += lam[0] * (x.x - ld) * tv.x;  cnt[0] += tv.x;
        colS[1] += lam[1] * (x.y - ld) * tv.y;  cnt[1] += tv.y;
        colS[2] += lam[2] * (x.z - ld) * tv.z;  cnt[2] += tv.z;
        colS[3] += lam[3] * (x.w - ld) * tv.w;  cnt[3] += tv.w;
    }

    // block reduction: 8 accumulators/thread -> 256 outputs (128 colS + 128 cnt)
    __shared__ float lds[8][THREADS];
#pragma unroll
    for (int i = 0; i < 4; ++i) {
        lds[i][t]     = colS[i];
        lds[4 + i][t] = cnt[i];
    }
    __syncthreads();

    const int q   = t >> 7;          // 0 = colS, 1 = cnt
    const int c   = t & 127;         // column
    const int cgr = c >> 2;
    const int acc = q * 4 + (c & 3);
    float s = 0.f;
#pragma unroll
    for (int r = 0; r < 8; ++r) s += lds[acc][r * 32 + cgr];
    atomicAdd(&ws[q * 128 + c], s);
}

__global__ void whxe_pass2(const float* __restrict__ ws, float* __restrict__ out)
{
    const int l = threadIdx.x;       // 64 lanes
    float v = 0.f;
#pragma unroll
    for (int c = l; c < N_NODES; c += 64) {
        const float w = (float)B_TOTAL / ((float)N_NODES * (ws[128 + c] + EPS));
        v += w * ws[c];
    }
#pragma unroll
    for (int off = 32; off; off >>= 1) v += __shfl_xor(v, off);
    if (l == 0) out[0] = -v / (float)B_TOTAL;
}

extern "C" void kernel_launch(void* const* d_in, const int* in_sizes, int n_in,
                              void* d_out, int out_size, void* d_ws, size_t ws_size,
                              hipStream_t stream) {
    const float* logits = (const float*)d_in[0];
    const float* truev  = (const float*)d_in[1];
    const float* depths = (const float*)d_in[2];
    // d_in[3] = group_ids; layout is repeat(arange(32),4) -> 4 consecutive
    // siblings per group, exploited structurally above.
    float* ws = (float*)d_ws;

    hipMemsetAsync(ws, 0, 256 * sizeof(float), stream);
    whxe_pass1<<<BLOCKS, THREADS, 0, stream>>>(logits, truev, depths, ws);
    whxe_pass2<<<1, 64, 0, stream>>>(ws, (float*)d_out);
}

// Round 2
// 32.258 us; speedup vs baseline: 1.6034x; 1.6034x over previous
//
#include <hip/hip_runtime.h>

// WHXE loss, round 2: kill the same-address atomic hotspot + deepen MLP.
//   colS[n] = sum_b lam[n] * logp[b,n] * true[b,n]
//   cnt[n]  = sum_b true[b,n]
//   loss    = -(1/B) * sum_n (B / (N*(cnt[n]+eps))) * colS[n]
// Sibling groups are 4 consecutive columns (group_ids = repeat(arange(32),4)),
// so one float4 load = one complete softmax group.

#define B_TOTAL 131072
#define N_NODES 128
#define ALPHA   0.5f
#define EPS     1e-10f

constexpr int BLOCKS         = 2048;                    // 8 blocks/CU -> 32 waves/CU
constexpr int THREADS        = 256;
constexpr int ROWS_PER_ITER  = THREADS / 32;            // 8
constexpr int ROWS_PER_BLOCK = B_TOTAL / BLOCKS;        // 64 contiguous rows/block
constexpr int ITERS          = ROWS_PER_BLOCK / ROWS_PER_ITER;  // 8, compile-time
constexpr int REPLICAS       = 32;                      // spread atomic targets 32x

__global__ __launch_bounds__(THREADS, 8) void whxe_pass1(
    const float* __restrict__ logits,
    const float* __restrict__ truev,
    const float* __restrict__ depths,
    float* __restrict__ ws)   // ws[rep][256]: [0..127]=colS, [128..255]=cnt
{
    const int t    = threadIdx.x;
    const int cg   = t & 31;          // column group 0..31 (4 cols each)
    const int rsub = t >> 5;          // row-within-iteration 0..7
    const int c0   = cg << 2;

    float lam[4];
#pragma unroll
    for (int i = 0; i < 4; ++i) lam[i] = __expf(-ALPHA * depths[c0 + i]);

    float colS[4] = {0.f, 0.f, 0.f, 0.f};
    float cnt [4] = {0.f, 0.f, 0.f, 0.f};

    const size_t base0 = (size_t)(blockIdx.x * ROWS_PER_BLOCK + rsub) * N_NODES + c0;
    const float* lp = logits + base0;
    const float* tp = truev  + base0;
    constexpr size_t STRIDE = (size_t)ROWS_PER_ITER * N_NODES;  // 1024 elems

    // 2-deep manual pipeline: next iteration's loads are in flight during compute
    float4 x  = *reinterpret_cast<const float4*>(lp);
    float4 tv = *reinterpret_cast<const float4*>(tp);
#pragma unroll
    for (int it = 0; it < ITERS; ++it) {
        float4 xn, tvn;
        if (it + 1 < ITERS) {
            xn  = *reinterpret_cast<const float4*>(lp + (size_t)(it + 1) * STRIDE);
            tvn = *reinterpret_cast<const float4*>(tp + (size_t)(it + 1) * STRIDE);
        }
        const float e0 = __expf(x.x), e1 = __expf(x.y),
                    e2 = __expf(x.z), e3 = __expf(x.w);
        const float ld = __logf(e0 + e1 + e2 + e3 + EPS);
        colS[0] += lam[0] * (x.x - ld) * tv.x;  cnt[0] += tv.x;
        colS[1] += lam[1] * (x.y - ld) * tv.y;  cnt[1] += tv.y;
        colS[2] += lam[2] * (x.z - ld) * tv.z;  cnt[2] += tv.z;
        colS[3] += lam[3] * (x.w - ld) * tv.w;  cnt[3] += tv.w;
        x = xn; tv = tvn;
    }

    // block reduction: 8 accumulators/thread -> 256 partials
    __shared__ float lds[8][THREADS];
#pragma unroll
    for (int i = 0; i < 4; ++i) {
        lds[i][t]     = colS[i];
        lds[4 + i][t] = cnt[i];
    }
    __syncthreads();

    const int q   = t >> 7;           // 0 = colS, 1 = cnt
    const int c   = t & 127;          // column
    const int acc = q * 4 + (c & 3);
    const int cgr = c >> 2;
    float s = 0.f;
#pragma unroll
    for (int r = 0; r < 8; ++r) s += lds[acc][r * 32 + cgr];

    // replica-spread atomics: 64 adds per address instead of 2048
    const int rep = blockIdx.x & (REPLICAS - 1);
    atomicAdd(&ws[rep * 256 + q * 128 + c], s);
}

__global__ __launch_bounds__(256) void whxe_pass2(
    const float* __restrict__ ws, float* __restrict__ out)
{
    const int t = threadIdx.x;        // 256
    float s = 0.f;
#pragma unroll
    for (int r = 0; r < REPLICAS; ++r) s += ws[r * 256 + t];

    __shared__ float red[256];
    red[t] = s;
    __syncthreads();

    float v = 0.f;
    if (t < 128) {
        const float w = (float)B_TOTAL / ((float)N_NODES * (red[128 + t] + EPS));
        v = w * red[t];
    }
    __syncthreads();
    red[t] = v;                        // t>=128 contribute 0
    __syncthreads();

    if (t < 64) {
        float r2 = red[t] + red[t + 64] + ((t < 128) ? red[t + 128] + red[t + 192] : 0.f);
#pragma unroll
        for (int off = 32; off; off >>= 1) r2 += __shfl_xor(r2, off);
        if (t == 0) out[0] = -r2 / (float)B_TOTAL;
    }
}

extern "C" void kernel_launch(void* const* d_in, const int* in_sizes, int n_in,
                              void* d_out, int out_size, void* d_ws, size_t ws_size,
                              hipStream_t stream) {
    const float* logits = (const float*)d_in[0];
    const float* truev  = (const float*)d_in[1];
    const float* depths = (const float*)d_in[2];
    float* ws = (float*)d_ws;

    hipMemsetAsync(ws, 0, REPLICAS * 256 * sizeof(float), stream);
    whxe_pass1<<<BLOCKS, THREADS, 0, stream>>>(logits, truev, depths, ws);
    whxe_pass2<<<1, 256, 0, stream>>>(ws, (float*)d_out);
}